// Round 18
// baseline (210.416 us; speedup 1.0000x reference)
//
#include <hip/hip_runtime.h>
#include <math.h>

#define NLIG 16384
#define NPROT 131072
#define NTOT (NLIG + NPROT)
#define NEDGE 2097152
#define NB 256
#define H 64
#define NBUCK 576      // NTOT = 576 * 256
#define BSHIFT 8       // bucket = dst >> 8
#define BCAP 4608      // padded bucket capacity (avg 3641, sd ~60 -> 16 sigma)
#define NPW 24         // 768 blocks x 8 waves x 24 nodes = 147456 = NTOT exactly

typedef short v4s __attribute__((ext_vector_type(4)));
typedef float v4f __attribute__((ext_vector_type(4)));

__device__ __forceinline__ unsigned short f2bf(float f) {
    unsigned int u = __float_as_uint(f);
    u += 0x7fff + ((u >> 16) & 1);   // RNE
    return (unsigned short)(u >> 16);
}
__device__ __forceinline__ float bf2f(unsigned short s) {
    return __uint_as_float(((unsigned int)s) << 16);
}
__device__ __forceinline__ float bflo(unsigned int u) {
    return __uint_as_float(u << 16);
}
__device__ __forceinline__ float bfhi(unsigned int u) {
    return __uint_as_float(u & 0xffff0000u);
}

// ---------------- prep2: wswz (0..23) || time_mlp (24..39) || zeroing (40) ----------------
__global__ __launch_bounds__(1024) void prep2_kernel(const float* __restrict__ t,
                                                     const float* __restrict__ Wt1, const float* __restrict__ bt1,
                                                     const float* __restrict__ Wt2, const float* __restrict__ bt2,
                                                     const float* __restrict__ W0, const float* __restrict__ W1,
                                                     const float* __restrict__ W2, const float* __restrict__ W3,
                                                     const float* __restrict__ W4, const float* __restrict__ W5,
                                                     unsigned short* __restrict__ wbuf,
                                                     float* __restrict__ t_emb,
                                                     unsigned int* __restrict__ zero_region) {
    int b = blockIdx.x, tid = threadIdx.x;
    if (b < 24) {
        const float* Ws[6] = {W0, W1, W2, W3, W4, W5};
        int tglob = b * 1024 + tid;
        int m = tglob >> 12, tt = tglob & 4095;
        int f = tt >> 8, l = (tt >> 2) & 63, i = tt & 3;
        int kt = f >> 2, ct = f & 3;
        int row = 16 * kt + 4 * (l >> 4) + i;
        int col = 16 * ct + (l & 15);
        wbuf[m * 4096 + tt] = f2bf(Ws[m][row * H + col]);
    } else if (b < 40) {
        __shared__ float emb_s[16][H];
        __shared__ float h1_s[16][H];
        int w = tid >> 6, h = tid & 63;
        int bb = (b - 24) * 16 + w;
        float tv = t[bb];
        int i = h & 31;
        float freq = expf((float)i * (-9.2103403719761836f / 31.0f));
        float e = tv * freq;
        emb_s[w][h] = (h < 32) ? sinf(e) : cosf(e);
        __syncthreads();
        float acc = bt1[h];
        #pragma unroll 8
        for (int k = 0; k < H; k++) acc += emb_s[w][k] * Wt1[k * H + h];
        float sig = 1.0f / (1.0f + expf(-acc));
        h1_s[w][h] = acc * sig;
        __syncthreads();
        float acc2 = bt2[h];
        #pragma unroll 8
        for (int k = 0; k < H; k++) acc2 += h1_s[w][k] * Wt2[k * H + h];
        t_emb[bb * H + h] = acc2;
    } else {
        // zero bcursor(576) + pooled(16384) + cnt(256) = 17216 dwords contiguous
        for (int i = tid; i < 17216; i += 1024) zero_region[i] = 0;
    }
}

// ---------------- fill (0..255, one-pass proven) || node_init (256..1407, 128 nodes/blk) ----------------
// Round-17's version had 9344 blocks at 2 blocks/CU -> 18 sequential launch
// rounds of tiny node_init blocks = the hidden 58 us. Rebalanced: 1408 blocks
// = 2.75 rounds; fill back to the proven 256x8192 one-pass geometry.
__global__ __launch_bounds__(1024) void fill_init_kernel(const int* __restrict__ edge_index,
                                                         unsigned int* __restrict__ bcursor,
                                                         unsigned int* __restrict__ bucketed,
                                                         const float* __restrict__ lig_feat,
                                                         const float* __restrict__ prot_feat,
                                                         const int* __restrict__ lig_batch,
                                                         const float* __restrict__ t_emb,
                                                         const float* __restrict__ W_lig,
                                                         const float* __restrict__ b_lig,
                                                         const float* __restrict__ W_prot,
                                                         const float* __restrict__ b_prot,
                                                         unsigned int* __restrict__ xb) {
    int b = blockIdx.x, tid = threadIdx.x;
    if (b < 256) {
        __shared__ unsigned int lh[NBUCK];
        __shared__ unsigned int lcur[NBUCK];
        __shared__ unsigned int gb[NBUCK];
        for (int i = tid; i < NBUCK; i += 1024) lh[i] = 0;
        __syncthreads();
        int e0 = b * 8192;
        int src[8], dst[8];
        #pragma unroll
        for (int k = 0; k < 8; k++) {
            src[k] = edge_index[e0 + k * 1024 + tid];
            dst[k] = edge_index[NEDGE + e0 + k * 1024 + tid];
            atomicAdd(&lh[dst[k] >> BSHIFT], 1);
        }
        __syncthreads();
        if (tid < NBUCK) {
            gb[tid] = atomicAdd(&bcursor[tid], lh[tid]);
            lcur[tid] = 0;
        }
        __syncthreads();
        #pragma unroll
        for (int k = 0; k < 8; k++) {
            int bb = dst[k] >> BSHIFT;
            unsigned int r = atomicAdd(&lcur[bb], 1);
            unsigned int slot = gb[bb] + r;
            if (slot < BCAP)
                bucketed[bb * BCAP + slot] =
                    (unsigned int)src[k] | ((unsigned int)(dst[k] & 255) << 18);
        }
    } else {
        // node_init: 128 nodes per block (8 iterations x 16 waves-worth)
        int base = (b - 256) * 128;
        int h = tid & 63;
        #pragma unroll
        for (int it = 0; it < 8; it++) {
            int node = base + it * 16 + (tid >> 6);
            float acc;
            if (node < NLIG) {
                int bb = lig_batch[node];
                acc = b_lig[h] + t_emb[bb * H + h];
                #pragma unroll
                for (int k = 0; k < 15; k++)
                    acc += lig_feat[node * 15 + k] * W_lig[k * H + h];
            } else {
                int p = node - NLIG;
                acc = b_prot[h];
                #pragma unroll
                for (int k = 0; k < 8; k++)
                    acc += prot_feat[p * 8 + k] * W_prot[k * H + h];
            }
            float e0 = __shfl(acc, 2 * (h & 31));
            float e1 = __shfl(acc, 2 * (h & 31) + 1);
            if (h < 32)
                xb[node * 32 + h] = (unsigned int)f2bf(e0) | ((unsigned int)f2bf(e1) << 16);
        }
    }
}

// ---------------- per-bucket counting sort -> csr_src + per-node [beg,end) ----------------
__global__ __launch_bounds__(1024) void bucket_csr_kernel(const unsigned int* __restrict__ bucketed,
                                                          const unsigned int* __restrict__ bcursor,
                                                          int* __restrict__ off,
                                                          int* __restrict__ ends,
                                                          int* __restrict__ csr_src) {
    __shared__ unsigned int stage[BCAP];   // 18 KB
    __shared__ unsigned int csr_l[BCAP];   // 18 KB
    __shared__ unsigned int lh[256];
    __shared__ unsigned int sc[256];
    __shared__ unsigned int lcur[256];
    int b = blockIdx.x, tid = threadIdx.x;
    unsigned int base = (unsigned int)b * BCAP;
    int cnt = (int)bcursor[b];
    if (cnt > BCAP) cnt = BCAP;   // 16-sigma guard, never triggers
    if (tid < 256) lh[tid] = 0;
    __syncthreads();
    for (int i = tid; i < cnt; i += 1024) {
        unsigned int v = bucketed[base + i];
        stage[i] = v;
        atomicAdd(&lh[v >> 18], 1);
    }
    __syncthreads();
    if (tid < 256) sc[tid] = lh[tid];
    __syncthreads();
    #pragma unroll
    for (int d = 1; d < 256; d <<= 1) {
        unsigned int v = (tid < 256 && tid >= (unsigned)d) ? sc[tid - d] : 0;
        __syncthreads();
        if (tid < 256) sc[tid] += v;
        __syncthreads();
    }
    if (tid < 256) {
        unsigned int excl = sc[tid] - lh[tid];
        lcur[tid] = excl;
        off[b * 256 + tid]  = (int)(base + excl);
        ends[b * 256 + tid] = (int)(base + excl + lh[tid]);
    }
    __syncthreads();
    for (int i = tid; i < cnt; i += 1024) {
        unsigned int v = stage[i];
        unsigned int p = atomicAdd(&lcur[v >> 18], 1);
        csr_l[p] = v & 0x3ffffu;
    }
    __syncthreads();
    for (int i = tid; i < cnt; i += 1024)
        csr_src[base + i] = (int)csr_l[i];
}

// accumulate one 16B quad of a neighbor row
#define ACC8(u)                                   \
    do {                                          \
        a0 += bflo((u).x); a1 += bfhi((u).x);     \
        a2 += bflo((u).y); a3 += bfhi((u).y);     \
        a4 += bflo((u).z); a5 += bfhi((u).z);     \
        a6 += bflo((u).w); a7 += bfhi((u).w);     \
    } while (0)

// 8-deep unconditional gather over one slot-group (round-12 proven: VGPR 40,
// no spill at waves/EU=6). Store into agg_s row AGGROW.
#define DO_GROUP(BEG, DEG, IDFIRST, AGGROW)                                     \
    {                                                                           \
        int idcur = (IDFIRST);                                                  \
        float a0 = 0.f, a1 = 0.f, a2 = 0.f, a3 = 0.f;                           \
        float a4 = 0.f, a5 = 0.f, a6 = 0.f, a7 = 0.f;                           \
        for (int jb = 0; jb < (DEG); jb += 8) {                                 \
            int idnxt = (jb + 8 + q < (DEG)) ? csr[(BEG) + jb + 8 + q] : -1;    \
            int n0 = __shfl(idcur, s * 8 + 0);                                  \
            int n1 = __shfl(idcur, s * 8 + 1);                                  \
            int n2 = __shfl(idcur, s * 8 + 2);                                  \
            int n3 = __shfl(idcur, s * 8 + 3);                                  \
            int n4 = __shfl(idcur, s * 8 + 4);                                  \
            int n5 = __shfl(idcur, s * 8 + 5);                                  \
            int n6 = __shfl(idcur, s * 8 + 6);                                  \
            int n7 = __shfl(idcur, s * 8 + 7);                                  \
            int c1 = (n1 >= 0) ? n1 : n0;                                       \
            int c2 = (n2 >= 0) ? n2 : n0;                                       \
            int c3 = (n3 >= 0) ? n3 : n0;                                       \
            int c4 = (n4 >= 0) ? n4 : n0;                                       \
            int c5 = (n5 >= 0) ? n5 : n0;                                       \
            int c6 = (n6 >= 0) ? n6 : n0;                                       \
            int c7 = (n7 >= 0) ? n7 : n0;                                       \
            uint4 u0 = *(const uint4*)&xb[n0 * 32 + q * 4];                     \
            uint4 u1 = *(const uint4*)&xb[c1 * 32 + q * 4];                     \
            uint4 u2 = *(const uint4*)&xb[c2 * 32 + q * 4];                     \
            uint4 u3 = *(const uint4*)&xb[c3 * 32 + q * 4];                     \
            uint4 u4 = *(const uint4*)&xb[c4 * 32 + q * 4];                     \
            uint4 u5 = *(const uint4*)&xb[c5 * 32 + q * 4];                     \
            uint4 u6 = *(const uint4*)&xb[c6 * 32 + q * 4];                     \
            uint4 u7 = *(const uint4*)&xb[c7 * 32 + q * 4];                     \
            if (n1 < 0) { u1.x = u1.y = u1.z = u1.w = 0; }                      \
            if (n2 < 0) { u2.x = u2.y = u2.z = u2.w = 0; }                      \
            if (n3 < 0) { u3.x = u3.y = u3.z = u3.w = 0; }                      \
            if (n4 < 0) { u4.x = u4.y = u4.z = u4.w = 0; }                      \
            if (n5 < 0) { u5.x = u5.y = u5.z = u5.w = 0; }                      \
            if (n6 < 0) { u6.x = u6.y = u6.z = u6.w = 0; }                      \
            if (n7 < 0) { u7.x = u7.y = u7.z = u7.w = 0; }                      \
            ACC8(u0); ACC8(u1); ACC8(u2); ACC8(u3);                             \
            ACC8(u4); ACC8(u5); ACC8(u6); ACC8(u7);                             \
            idcur = idnxt;                                                      \
        }                                                                       \
        unsigned int p0 = (unsigned int)f2bf(a0) | ((unsigned int)f2bf(a1) << 16); \
        unsigned int p1 = (unsigned int)f2bf(a2) | ((unsigned int)f2bf(a3) << 16); \
        unsigned int p2 = (unsigned int)f2bf(a4) | ((unsigned int)f2bf(a5) << 16); \
        unsigned int p3 = (unsigned int)f2bf(a6) | ((unsigned int)f2bf(a7) << 16); \
        *(uint4*)&agg_s[(AGGROW) * 72 + q * 8] = make_uint4(p0, p1, p2, p3);    \
    }

// ---------------- fused conv (layers 1,2): 24 nodes/wave, 8-deep gather ----------------
// ROUND-12 PROVEN CONFIG: 768 blocks x 512 thr = 6144 waves x 24 nodes = NTOT;
// 3 blocks/CU, waves/EU=6 -> 85-reg budget fits VGPR 40 + 32 AGPR, NO SPILL.
// (512,8) forces spills (round 13: WRITE 38->75 MB, 52.5->69.7 us). Do not tighten.
__global__ __launch_bounds__(512, 6) void conv_kernel(const int* __restrict__ off,
                                                      const int* __restrict__ ends,
                                                      const int* __restrict__ csr,
                                                      const unsigned int* __restrict__ xb,
                                                      const unsigned short* __restrict__ wbuf,
                                                      const float* __restrict__ brel,
                                                      unsigned int* __restrict__ xob) {
    __shared__ unsigned int wlds[4096];            // 16 KB
    __shared__ unsigned short agg_s[8 * NPW * 72]; // 27 KB
    const int tid = threadIdx.x;
    const int w = tid >> 6, l = tid & 63;
    const unsigned int* wsrc = (const unsigned int*)wbuf;
    #pragma unroll
    for (int i = 0; i < 8; i++) wlds[i * 512 + tid] = wsrc[i * 512 + tid];

    const int s = l >> 3, q = l & 7;
    const int lrow = l & 15, g16 = l >> 4, g4 = 4 * (l >> 4);
    const int gwid = blockIdx.x * 8 + w;
    const int node0w = gwid * NPW;

    int bvv = (l < NPW) ? off[node0w + l] : 0;
    int evv = (l < NPW) ? ends[node0w + l] : 0;

    int b0 = __shfl(bvv, s),      d0 = __shfl(evv, s) - b0;
    int b1 = __shfl(bvv, 8 + s),  d1 = __shfl(evv, 8 + s) - b1;
    int b2 = __shfl(bvv, 16 + s), d2 = __shfl(evv, 16 + s) - b2;
    int id0 = (q < d0) ? csr[b0 + q] : -1;
    int id1 = (q < d1) ? csr[b1 + q] : -1;
    int id2 = (q < d2) ? csr[b2 + q] : -1;

    __syncthreads();   // wlds ready

    float bv[4];
    #pragma unroll
    for (int ct = 0; ct < 4; ct++) bv[ct] = brel[ct * 16 + lrow];

    DO_GROUP(b0, d0, id0, w * NPW + s)
    DO_GROUP(b1, d1, id1, w * NPW + 8 + s)
    DO_GROUP(b2, d2, id2, w * NPW + 16 + s)

    __builtin_amdgcn_wave_barrier();

    // ---- MFMA pass 1: rows 0..15 ----
    v4s ax[4];
    #pragma unroll
    for (int kt = 0; kt < 4; kt++)
        ax[kt] = *(const v4s*)&xb[(node0w + lrow) * 32 + kt * 8 + g16 * 2];
    v4f acc[4];
    #pragma unroll
    for (int ct = 0; ct < 4; ct++) acc[ct] = (v4f){0.f, 0.f, 0.f, 0.f};
    #pragma unroll
    for (int kt = 0; kt < 4; kt++) {
        v4s a_agg = *(const v4s*)&agg_s[(w * NPW + lrow) * 72 + kt * 16 + g4];
        #pragma unroll
        for (int ct = 0; ct < 4; ct++) {
            int f = kt * 4 + ct;
            v4s wr = *(const v4s*)&wlds[f * 128 + l * 2];
            v4s wo = *(const v4s*)&wlds[2048 + f * 128 + l * 2];
            acc[ct] = __builtin_amdgcn_mfma_f32_16x16x16bf16_1k(a_agg, wr, acc[ct], 0, 0, 0);
            acc[ct] = __builtin_amdgcn_mfma_f32_16x16x16bf16_1k(ax[kt], wo, acc[ct], 0, 0, 0);
        }
    }
    // ---- MFMA pass 2: rows 16..23 (A rows replicated x2; keep D rows 0..7) ----
    const int r2row = 16 + (l & 7);
    v4s ax2[4];
    #pragma unroll
    for (int kt = 0; kt < 4; kt++)
        ax2[kt] = *(const v4s*)&xb[(node0w + r2row) * 32 + kt * 8 + g16 * 2];
    v4f acc2[4];
    #pragma unroll
    for (int ct = 0; ct < 4; ct++) acc2[ct] = (v4f){0.f, 0.f, 0.f, 0.f};
    #pragma unroll
    for (int kt = 0; kt < 4; kt++) {
        v4s a_agg2 = *(const v4s*)&agg_s[(w * NPW + r2row) * 72 + kt * 16 + g4];
        #pragma unroll
        for (int ct = 0; ct < 4; ct++) {
            int f = kt * 4 + ct;
            v4s wr = *(const v4s*)&wlds[f * 128 + l * 2];
            v4s wo = *(const v4s*)&wlds[2048 + f * 128 + l * 2];
            acc2[ct] = __builtin_amdgcn_mfma_f32_16x16x16bf16_1k(a_agg2, wr, acc2[ct], 0, 0, 0);
            acc2[ct] = __builtin_amdgcn_mfma_f32_16x16x16bf16_1k(ax2[kt], wo, acc2[ct], 0, 0, 0);
        }
    }
    __builtin_amdgcn_wave_barrier();

    // ---- epilogue into own agg rows ----
    #pragma unroll
    for (int ct = 0; ct < 4; ct++) {
        #pragma unroll
        for (int r = 0; r < 4; r++)
            agg_s[(w * NPW + g4 + r) * 72 + ct * 16 + lrow] = f2bf(acc[ct][r] + bv[ct]);
    }
    if (g16 < 2) {   // pass-2 valid D rows 0..7 -> nodes 16..23
        #pragma unroll
        for (int ct = 0; ct < 4; ct++) {
            #pragma unroll
            for (int r = 0; r < 4; r++)
                agg_s[(w * NPW + 16 + g4 + r) * 72 + ct * 16 + lrow] =
                    f2bf(acc2[ct][r] + bv[ct]);
        }
    }
    __builtin_amdgcn_wave_barrier();

    // ---- wave-local coalesced writeout: rows 0..15, then rows 16..23 ----
    {
        int row = l >> 2, qq = l & 3;
        const unsigned int* srcp = (const unsigned int*)&agg_s[(w * NPW + row) * 72 + qq * 16];
        uint4 v0 = *(const uint4*)(srcp);
        uint4 v1 = *(const uint4*)(srcp + 4);
        *(uint4*)&xob[(node0w + row) * 32 + qq * 8] = v0;
        *(uint4*)&xob[(node0w + row) * 32 + qq * 8 + 4] = v1;
    }
    {
        int row = 16 + (l >> 3), qq = l & 7;
        *(uint4*)&xob[(node0w + row) * 32 + qq * 4] =
            *(const uint4*)&agg_s[(w * NPW + row) * 72 + qq * 8];
    }
}

// ---------------- conv layer 3 (ligand rows only) + fused pooling ----------------
__global__ __launch_bounds__(512, 6) void conv_lig_kernel(const int* __restrict__ off,
                                                          const int* __restrict__ ends,
                                                          const int* __restrict__ csr,
                                                          const unsigned int* __restrict__ xb,
                                                          const unsigned short* __restrict__ wbuf,
                                                          const float* __restrict__ brel,
                                                          const int* __restrict__ lig_batch,
                                                          float* __restrict__ pooled,
                                                          float* __restrict__ cnt) {
    __shared__ unsigned int wlds[4096];          // 16 KB
    __shared__ unsigned short agg_s[8 * 8 * 72]; // 9 KB
    const int tid = threadIdx.x;
    const int w = tid >> 6, l = tid & 63;
    const unsigned int* wsrc = (const unsigned int*)wbuf;
    #pragma unroll
    for (int i = 0; i < 8; i++) wlds[i * 512 + tid] = wsrc[i * 512 + tid];

    const int s = l >> 3, q = l & 7;
    const int lrow = l & 15, g16 = l >> 4, g4 = 4 * (l >> 4);
    const int gwid = blockIdx.x * 8 + w;
    const int node0w = gwid * 8;

    int bvv = (l < 8) ? off[node0w + l] : 0;
    int evv = (l < 8) ? ends[node0w + l] : 0;
    int b0 = __shfl(bvv, s), d0 = __shfl(evv, s) - b0;
    int id0 = (q < d0) ? csr[b0 + q] : -1;

    __syncthreads();   // wlds ready

    float bv[4];
    #pragma unroll
    for (int ct = 0; ct < 4; ct++) bv[ct] = brel[ct * 16 + lrow];

    DO_GROUP(b0, d0, id0, w * 8 + s)

    __builtin_amdgcn_wave_barrier();

    // ---- MFMA: A rows duplicated (row = lrow&7) -> D rows 0..7 valid ----
    const int arow = lrow & 7;
    v4s ax[4];
    #pragma unroll
    for (int kt = 0; kt < 4; kt++)
        ax[kt] = *(const v4s*)&xb[(node0w + arow) * 32 + kt * 8 + g16 * 2];
    v4f acc[4];
    #pragma unroll
    for (int ct = 0; ct < 4; ct++) acc[ct] = (v4f){0.f, 0.f, 0.f, 0.f};
    #pragma unroll
    for (int kt = 0; kt < 4; kt++) {
        v4s a_agg = *(const v4s*)&agg_s[(w * 8 + arow) * 72 + kt * 16 + g4];
        #pragma unroll
        for (int ct = 0; ct < 4; ct++) {
            int f = kt * 4 + ct;
            v4s wr = *(const v4s*)&wlds[f * 128 + l * 2];
            v4s wo = *(const v4s*)&wlds[2048 + f * 128 + l * 2];
            acc[ct] = __builtin_amdgcn_mfma_f32_16x16x16bf16_1k(a_agg, wr, acc[ct], 0, 0, 0);
            acc[ct] = __builtin_amdgcn_mfma_f32_16x16x16bf16_1k(ax[kt], wo, acc[ct], 0, 0, 0);
        }
    }

    // ---- fused pooling epilogue (f32 atomics; D rows 0..7 only) ----
    if (g16 < 2) {
        #pragma unroll
        for (int r = 0; r < 4; r++) {
            int node = node0w + g4 + r;
            int bb = lig_batch[node];
            #pragma unroll
            for (int ct = 0; ct < 4; ct++)
                unsafeAtomicAdd(&pooled[bb * H + ct * 16 + lrow], acc[ct][r] + bv[ct]);
            if (lrow == 0) unsafeAtomicAdd(&cnt[bb], 1.0f);
        }
    }
}

// ---------------- readout ----------------
__global__ void readout_kernel(const float* __restrict__ pooled, const float* __restrict__ cnt,
                               const float* __restrict__ Wro1, const float* __restrict__ bro1,
                               const float* __restrict__ Wro2, const float* __restrict__ bro2,
                               float* __restrict__ out) {
    __shared__ float pm[4][H];
    int w = threadIdx.x >> 6;
    int h = threadIdx.x & 63;
    int b = blockIdx.x * 4 + w;
    float c = fmaxf(cnt[b], 1.0f);
    pm[w][h] = pooled[b * H + h] / c;
    __syncthreads();
    float acc = bro1[h];
    #pragma unroll 8
    for (int k = 0; k < H; k++) acc += pm[w][k] * Wro1[k * H + h];
    float sig = 1.0f / (1.0f + expf(-acc));
    float s = acc * sig;
    float r = s * Wro2[h];
    #pragma unroll
    for (int off = 32; off; off >>= 1) r += __shfl_down(r, off);
    if (h == 0) out[b] = r + bro2[0];
}

extern "C" void kernel_launch(void* const* d_in, const int* in_sizes, int n_in,
                              void* d_out, int out_size, void* d_ws, size_t ws_size,
                              hipStream_t stream) {
    const float* lig_feat  = (const float*)d_in[1];
    const float* prot_feat = (const float*)d_in[3];
    const float* t         = (const float*)d_in[4];
    const int*   lig_batch = (const int*)d_in[5];
    const int*   edge_index= (const int*)d_in[7];
    const float* W_lig  = (const float*)d_in[8];
    const float* b_lig  = (const float*)d_in[9];
    const float* W_prot = (const float*)d_in[10];
    const float* b_prot = (const float*)d_in[11];
    const float* Wt1 = (const float*)d_in[12];
    const float* bt1 = (const float*)d_in[13];
    const float* Wt2 = (const float*)d_in[14];
    const float* bt2 = (const float*)d_in[15];
    const float* Wrel[3]  = {(const float*)d_in[16], (const float*)d_in[19], (const float*)d_in[22]};
    const float* brel[3]  = {(const float*)d_in[17], (const float*)d_in[20], (const float*)d_in[23]};
    const float* Wroot[3] = {(const float*)d_in[18], (const float*)d_in[21], (const float*)d_in[24]};
    const float* Wro1 = (const float*)d_in[25];
    const float* bro1 = (const float*)d_in[26];
    const float* Wro2 = (const float*)d_in[27];
    const float* bro2 = (const float*)d_in[28];
    float* out = (float*)d_out;

    char* ws = (char*)d_ws;
    int*            off_a   = (int*)(ws);                       // NTOT ints
    int*            ends_a  = (int*)(ws + 655360);              // NTOT ints
    unsigned int*   bcursor = (unsigned int*)(ws + 1310720);    // 2304 B   ┐ contiguous
    float*          pooled  = (float*)(ws + 1313024);           // 65536 B  │ zero region
    float*          cnt     = (float*)(ws + 1378560);           // 1024 B   ┘ 68864 B
    float*          t_emb   = (float*)(ws + 1380352);           // 64 KB
    unsigned short* wbuf    = (unsigned short*)(ws + 1572864);  // 48 KB
    int*            csr_src = (int*)(ws + 2097152);             // 10.6 MB padded
    unsigned int*   bucketed= (unsigned int*)(ws + 14680064);   // 10.6 MB padded
    unsigned int*   xb0     = (unsigned int*)(ws + 27262976);   // 18 MB
    unsigned int*   xb1     = (unsigned int*)(ws + 46137344);   // 18 MB

    // prep2: wswz || time_mlp || zero(bcursor,pooled,cnt)
    prep2_kernel<<<41, 1024, 0, stream>>>(t, Wt1, bt1, Wt2, bt2,
                                          Wrel[0], Wroot[0], Wrel[1], Wroot[1], Wrel[2], Wroot[2],
                                          wbuf, t_emb, bcursor);

    // fill (256 blocks, one-pass) || node_init (1152 blocks x 128 nodes)
    fill_init_kernel<<<256 + NTOT / 128, 1024, 0, stream>>>(edge_index, bcursor, bucketed,
                                                            lig_feat, prot_feat, lig_batch, t_emb,
                                                            W_lig, b_lig, W_prot, b_prot, xb0);

    // per-bucket counting sort -> CSR
    bucket_csr_kernel<<<NBUCK, 1024, 0, stream>>>(bucketed, bcursor, off_a, ends_a, csr_src);

    // ---- conv layers 1,2 (all nodes; round-12 proven config) ----
    conv_kernel<<<768, 512, 0, stream>>>(off_a, ends_a, csr_src, xb0,
                                         wbuf, brel[0], xb1);
    conv_kernel<<<768, 512, 0, stream>>>(off_a, ends_a, csr_src, xb1,
                                         wbuf + 8192, brel[1], xb0);
    // ---- conv layer 3: ligand rows only, fused pooling ----
    conv_lig_kernel<<<NLIG / 64, 512, 0, stream>>>(off_a, ends_a, csr_src, xb0,
                                                   wbuf + 16384, brel[2], lig_batch,
                                                   pooled, cnt);

    readout_kernel<<<NB / 4, 256, 0, stream>>>(pooled, cnt, Wro1, bro1, Wro2, bro2, out);
}

// Round 19
// 205.526 us; speedup vs baseline: 1.0238x; 1.0238x over previous
//
#include <hip/hip_runtime.h>
#include <math.h>

#define NLIG 16384
#define NPROT 131072
#define NTOT (NLIG + NPROT)
#define NEDGE 2097152
#define NB 256
#define H 64
#define NBUCK 576      // NTOT = 576 * 256
#define BSHIFT 8       // bucket = dst >> 8
#define BCAP 4608      // padded bucket capacity (avg 3641, sd ~60 -> 16 sigma)
#define NPW 24         // 768 blocks x 8 waves x 24 nodes = 147456 = NTOT exactly

typedef short v4s __attribute__((ext_vector_type(4)));
typedef float v4f __attribute__((ext_vector_type(4)));

__device__ __forceinline__ unsigned short f2bf(float f) {
    unsigned int u = __float_as_uint(f);
    u += 0x7fff + ((u >> 16) & 1);   // RNE
    return (unsigned short)(u >> 16);
}
__device__ __forceinline__ float bf2f(unsigned short s) {
    return __uint_as_float(((unsigned int)s) << 16);
}
__device__ __forceinline__ float bflo(unsigned int u) {
    return __uint_as_float(u << 16);
}
__device__ __forceinline__ float bfhi(unsigned int u) {
    return __uint_as_float(u & 0xffff0000u);
}

// ---------------- prep2: wswz (0..23) || time_mlp (24..39) || zeroing (40) ----------------
__global__ __launch_bounds__(1024) void prep2_kernel(const float* __restrict__ t,
                                                     const float* __restrict__ Wt1, const float* __restrict__ bt1,
                                                     const float* __restrict__ Wt2, const float* __restrict__ bt2,
                                                     const float* __restrict__ W0, const float* __restrict__ W1,
                                                     const float* __restrict__ W2, const float* __restrict__ W3,
                                                     const float* __restrict__ W4, const float* __restrict__ W5,
                                                     unsigned short* __restrict__ wbuf,
                                                     float* __restrict__ t_emb,
                                                     unsigned int* __restrict__ zero_region) {
    int b = blockIdx.x, tid = threadIdx.x;
    if (b < 24) {
        const float* Ws[6] = {W0, W1, W2, W3, W4, W5};
        int tglob = b * 1024 + tid;
        int m = tglob >> 12, tt = tglob & 4095;
        int f = tt >> 8, l = (tt >> 2) & 63, i = tt & 3;
        int kt = f >> 2, ct = f & 3;
        int row = 16 * kt + 4 * (l >> 4) + i;
        int col = 16 * ct + (l & 15);
        wbuf[m * 4096 + tt] = f2bf(Ws[m][row * H + col]);
    } else if (b < 40) {
        __shared__ float emb_s[16][H];
        __shared__ float h1_s[16][H];
        int w = tid >> 6, h = tid & 63;
        int bb = (b - 24) * 16 + w;
        float tv = t[bb];
        int i = h & 31;
        float freq = expf((float)i * (-9.2103403719761836f / 31.0f));
        float e = tv * freq;
        emb_s[w][h] = (h < 32) ? sinf(e) : cosf(e);
        __syncthreads();
        float acc = bt1[h];
        #pragma unroll 8
        for (int k = 0; k < H; k++) acc += emb_s[w][k] * Wt1[k * H + h];
        float sig = 1.0f / (1.0f + expf(-acc));
        h1_s[w][h] = acc * sig;
        __syncthreads();
        float acc2 = bt2[h];
        #pragma unroll 8
        for (int k = 0; k < H; k++) acc2 += h1_s[w][k] * Wt2[k * H + h];
        t_emb[bb * H + h] = acc2;
    } else {
        // zero bcursor(576) + pooled(16384) + cnt(256) = 17216 dwords contiguous
        for (int i = tid; i < 17216; i += 1024) zero_region[i] = 0;
    }
}

// ---------------- fill (per-wave privatized) || node_init, role-interleaved ----------------
// 1408 blocks = 128 groups x 11: pos<2 -> fill (256 blocks), else init (1152).
// Interleaving spreads fill blocks across ALL CUs (previously clustered on
// ~half at 2-resident -> 2x wall). Fill uses per-wave private 576-counter
// segments: hist/rank LDS atomics never collide across waves.
__global__ __launch_bounds__(1024) void fill_init_kernel(const int* __restrict__ edge_index,
                                                         unsigned int* __restrict__ bcursor,
                                                         unsigned int* __restrict__ bucketed,
                                                         const float* __restrict__ lig_feat,
                                                         const float* __restrict__ prot_feat,
                                                         const int* __restrict__ lig_batch,
                                                         const float* __restrict__ t_emb,
                                                         const float* __restrict__ W_lig,
                                                         const float* __restrict__ b_lig,
                                                         const float* __restrict__ W_prot,
                                                         const float* __restrict__ b_prot,
                                                         unsigned int* __restrict__ xb) {
    int b = blockIdx.x, tid = threadIdx.x;
    int grp = b / 11, pos = b - grp * 11;
    if (pos < 2) {
        // ---- fill block fid in [0,256): 8192 edges ----
        __shared__ unsigned int seg[16 * NBUCK];   // 36 KB: per-wave counter segments
        __shared__ unsigned int gb[NBUCK];
        int fid = grp * 2 + pos;
        int w = tid >> 6;
        for (int i = tid; i < 16 * NBUCK; i += 1024) seg[i] = 0;
        __syncthreads();
        int e0 = fid * 8192;
        int src[8], dst[8];
        #pragma unroll
        for (int k = 0; k < 8; k++) {
            src[k] = edge_index[e0 + k * 1024 + tid];
            dst[k] = edge_index[NEDGE + e0 + k * 1024 + tid];
            atomicAdd(&seg[w * NBUCK + (dst[k] >> BSHIFT)], 1);   // private segment
        }
        __syncthreads();
        if (tid < NBUCK) {
            unsigned int tot = 0;
            #pragma unroll
            for (int ww = 0; ww < 16; ww++) {       // serial exclusive over waves
                unsigned int c = seg[ww * NBUCK + tid];
                seg[ww * NBUCK + tid] = tot;
                tot += c;
            }
            gb[tid] = atomicAdd(&bcursor[tid], tot);
        }
        __syncthreads();
        #pragma unroll
        for (int k = 0; k < 8; k++) {
            int bb = dst[k] >> BSHIFT;
            unsigned int r = atomicAdd(&seg[w * NBUCK + bb], 1);  // private rank
            unsigned int slot = gb[bb] + r;
            if (slot < BCAP)
                bucketed[bb * BCAP + slot] =
                    (unsigned int)src[k] | ((unsigned int)(dst[k] & 255) << 18);
        }
    } else {
        // ---- node_init block ib in [0,1152): 128 nodes ----
        int ib = grp * 9 + (pos - 2);
        int base = ib * 128;
        int h = tid & 63;
        #pragma unroll
        for (int it = 0; it < 8; it++) {
            int node = base + it * 16 + (tid >> 6);
            float acc;
            if (node < NLIG) {
                int bb = lig_batch[node];
                acc = b_lig[h] + t_emb[bb * H + h];
                #pragma unroll
                for (int k = 0; k < 15; k++)
                    acc += lig_feat[node * 15 + k] * W_lig[k * H + h];
            } else {
                int p = node - NLIG;
                acc = b_prot[h];
                #pragma unroll
                for (int k = 0; k < 8; k++)
                    acc += prot_feat[p * 8 + k] * W_prot[k * H + h];
            }
            float e0 = __shfl(acc, 2 * (h & 31));
            float e1 = __shfl(acc, 2 * (h & 31) + 1);
            if (h < 32)
                xb[node * 32 + h] = (unsigned int)f2bf(e0) | ((unsigned int)f2bf(e1) << 16);
        }
    }
}

// ---------------- per-bucket counting sort (per-wave privatized) ----------------
__global__ __launch_bounds__(1024) void bucket_csr_kernel(const unsigned int* __restrict__ bucketed,
                                                          const unsigned int* __restrict__ bcursor,
                                                          int* __restrict__ off,
                                                          int* __restrict__ ends,
                                                          int* __restrict__ csr_src) {
    __shared__ unsigned int stage[BCAP];     // 18 KB
    __shared__ unsigned int csr_l[BCAP];     // 18 KB
    __shared__ unsigned int seg[16 * 256];   // 16 KB per-wave node counters
    __shared__ unsigned int sc[256];
    int b = blockIdx.x, tid = threadIdx.x;
    int w = tid >> 6;
    unsigned int base = (unsigned int)b * BCAP;
    int cnt = (int)bcursor[b];
    if (cnt > BCAP) cnt = BCAP;   // 16-sigma guard, never triggers
    for (int i = tid; i < 16 * 256; i += 1024) seg[i] = 0;
    __syncthreads();
    for (int i = tid; i < cnt; i += 1024) {
        unsigned int v = bucketed[base + i];
        stage[i] = v;
        atomicAdd(&seg[w * 256 + (v >> 18)], 1);   // private segment
    }
    __syncthreads();
    unsigned int tot = 0;
    if (tid < 256) {
        #pragma unroll
        for (int ww = 0; ww < 16; ww++) {          // serial exclusive over waves
            unsigned int c = seg[ww * 256 + tid];
            seg[ww * 256 + tid] = tot;
            tot += c;
        }
        sc[tid] = tot;
    }
    __syncthreads();
    #pragma unroll
    for (int d = 1; d < 256; d <<= 1) {
        unsigned int v = (tid < 256 && tid >= (unsigned)d) ? sc[tid - d] : 0;
        __syncthreads();
        if (tid < 256) sc[tid] += v;
        __syncthreads();
    }
    if (tid < 256) {
        unsigned int excl = sc[tid] - tot;         // exclusive over nodes
        off[b * 256 + tid]  = (int)(base + excl);
        ends[b * 256 + tid] = (int)(base + excl + tot);
        #pragma unroll
        for (int ww = 0; ww < 16; ww++) seg[ww * 256 + tid] += excl;
    }
    __syncthreads();
    for (int i = tid; i < cnt; i += 1024) {
        unsigned int v = stage[i];
        unsigned int p = atomicAdd(&seg[w * 256 + (v >> 18)], 1);
        csr_l[p] = v & 0x3ffffu;
    }
    __syncthreads();
    for (int i = tid; i < cnt; i += 1024)
        csr_src[base + i] = (int)csr_l[i];
}

// accumulate one 16B quad of a neighbor row
#define ACC8(u)                                   \
    do {                                          \
        a0 += bflo((u).x); a1 += bfhi((u).x);     \
        a2 += bflo((u).y); a3 += bfhi((u).y);     \
        a4 += bflo((u).z); a5 += bfhi((u).z);     \
        a6 += bflo((u).w); a7 += bfhi((u).w);     \
    } while (0)

// 8-deep unconditional gather over one slot-group (round-12 proven: VGPR 40,
// no spill at waves/EU=6). Store into agg_s row AGGROW.
#define DO_GROUP(BEG, DEG, IDFIRST, AGGROW)                                     \
    {                                                                           \
        int idcur = (IDFIRST);                                                  \
        float a0 = 0.f, a1 = 0.f, a2 = 0.f, a3 = 0.f;                           \
        float a4 = 0.f, a5 = 0.f, a6 = 0.f, a7 = 0.f;                           \
        for (int jb = 0; jb < (DEG); jb += 8) {                                 \
            int idnxt = (jb + 8 + q < (DEG)) ? csr[(BEG) + jb + 8 + q] : -1;    \
            int n0 = __shfl(idcur, s * 8 + 0);                                  \
            int n1 = __shfl(idcur, s * 8 + 1);                                  \
            int n2 = __shfl(idcur, s * 8 + 2);                                  \
            int n3 = __shfl(idcur, s * 8 + 3);                                  \
            int n4 = __shfl(idcur, s * 8 + 4);                                  \
            int n5 = __shfl(idcur, s * 8 + 5);                                  \
            int n6 = __shfl(idcur, s * 8 + 6);                                  \
            int n7 = __shfl(idcur, s * 8 + 7);                                  \
            int c1 = (n1 >= 0) ? n1 : n0;                                       \
            int c2 = (n2 >= 0) ? n2 : n0;                                       \
            int c3 = (n3 >= 0) ? n3 : n0;                                       \
            int c4 = (n4 >= 0) ? n4 : n0;                                       \
            int c5 = (n5 >= 0) ? n5 : n0;                                       \
            int c6 = (n6 >= 0) ? n6 : n0;                                       \
            int c7 = (n7 >= 0) ? n7 : n0;                                       \
            uint4 u0 = *(const uint4*)&xb[n0 * 32 + q * 4];                     \
            uint4 u1 = *(const uint4*)&xb[c1 * 32 + q * 4];                     \
            uint4 u2 = *(const uint4*)&xb[c2 * 32 + q * 4];                     \
            uint4 u3 = *(const uint4*)&xb[c3 * 32 + q * 4];                     \
            uint4 u4 = *(const uint4*)&xb[c4 * 32 + q * 4];                     \
            uint4 u5 = *(const uint4*)&xb[c5 * 32 + q * 4];                     \
            uint4 u6 = *(const uint4*)&xb[c6 * 32 + q * 4];                     \
            uint4 u7 = *(const uint4*)&xb[c7 * 32 + q * 4];                     \
            if (n1 < 0) { u1.x = u1.y = u1.z = u1.w = 0; }                      \
            if (n2 < 0) { u2.x = u2.y = u2.z = u2.w = 0; }                      \
            if (n3 < 0) { u3.x = u3.y = u3.z = u3.w = 0; }                      \
            if (n4 < 0) { u4.x = u4.y = u4.z = u4.w = 0; }                      \
            if (n5 < 0) { u5.x = u5.y = u5.z = u5.w = 0; }                      \
            if (n6 < 0) { u6.x = u6.y = u6.z = u6.w = 0; }                      \
            if (n7 < 0) { u7.x = u7.y = u7.z = u7.w = 0; }                      \
            ACC8(u0); ACC8(u1); ACC8(u2); ACC8(u3);                             \
            ACC8(u4); ACC8(u5); ACC8(u6); ACC8(u7);                             \
            idcur = idnxt;                                                      \
        }                                                                       \
        unsigned int p0 = (unsigned int)f2bf(a0) | ((unsigned int)f2bf(a1) << 16); \
        unsigned int p1 = (unsigned int)f2bf(a2) | ((unsigned int)f2bf(a3) << 16); \
        unsigned int p2 = (unsigned int)f2bf(a4) | ((unsigned int)f2bf(a5) << 16); \
        unsigned int p3 = (unsigned int)f2bf(a6) | ((unsigned int)f2bf(a7) << 16); \
        *(uint4*)&agg_s[(AGGROW) * 72 + q * 8] = make_uint4(p0, p1, p2, p3);    \
    }

// ---------------- fused conv (layers 1,2): 24 nodes/wave, 8-deep gather ----------------
// ROUND-12 PROVEN CONFIG: 768 blocks x 512 thr = 6144 waves x 24 nodes = NTOT;
// 3 blocks/CU, waves/EU=6 -> 85-reg budget fits VGPR 40 + 32 AGPR, NO SPILL.
// (512,8) forces spills (round 13: WRITE 38->75 MB, 52.5->69.7 us). Do not tighten.
__global__ __launch_bounds__(512, 6) void conv_kernel(const int* __restrict__ off,
                                                      const int* __restrict__ ends,
                                                      const int* __restrict__ csr,
                                                      const unsigned int* __restrict__ xb,
                                                      const unsigned short* __restrict__ wbuf,
                                                      const float* __restrict__ brel,
                                                      unsigned int* __restrict__ xob) {
    __shared__ unsigned int wlds[4096];            // 16 KB
    __shared__ unsigned short agg_s[8 * NPW * 72]; // 27 KB
    const int tid = threadIdx.x;
    const int w = tid >> 6, l = tid & 63;
    const unsigned int* wsrc = (const unsigned int*)wbuf;
    #pragma unroll
    for (int i = 0; i < 8; i++) wlds[i * 512 + tid] = wsrc[i * 512 + tid];

    const int s = l >> 3, q = l & 7;
    const int lrow = l & 15, g16 = l >> 4, g4 = 4 * (l >> 4);
    const int gwid = blockIdx.x * 8 + w;
    const int node0w = gwid * NPW;

    int bvv = (l < NPW) ? off[node0w + l] : 0;
    int evv = (l < NPW) ? ends[node0w + l] : 0;

    int b0 = __shfl(bvv, s),      d0 = __shfl(evv, s) - b0;
    int b1 = __shfl(bvv, 8 + s),  d1 = __shfl(evv, 8 + s) - b1;
    int b2 = __shfl(bvv, 16 + s), d2 = __shfl(evv, 16 + s) - b2;
    int id0 = (q < d0) ? csr[b0 + q] : -1;
    int id1 = (q < d1) ? csr[b1 + q] : -1;
    int id2 = (q < d2) ? csr[b2 + q] : -1;

    __syncthreads();   // wlds ready

    float bv[4];
    #pragma unroll
    for (int ct = 0; ct < 4; ct++) bv[ct] = brel[ct * 16 + lrow];

    DO_GROUP(b0, d0, id0, w * NPW + s)
    DO_GROUP(b1, d1, id1, w * NPW + 8 + s)
    DO_GROUP(b2, d2, id2, w * NPW + 16 + s)

    __builtin_amdgcn_wave_barrier();

    // ---- MFMA pass 1: rows 0..15 ----
    v4s ax[4];
    #pragma unroll
    for (int kt = 0; kt < 4; kt++)
        ax[kt] = *(const v4s*)&xb[(node0w + lrow) * 32 + kt * 8 + g16 * 2];
    v4f acc[4];
    #pragma unroll
    for (int ct = 0; ct < 4; ct++) acc[ct] = (v4f){0.f, 0.f, 0.f, 0.f};
    #pragma unroll
    for (int kt = 0; kt < 4; kt++) {
        v4s a_agg = *(const v4s*)&agg_s[(w * NPW + lrow) * 72 + kt * 16 + g4];
        #pragma unroll
        for (int ct = 0; ct < 4; ct++) {
            int f = kt * 4 + ct;
            v4s wr = *(const v4s*)&wlds[f * 128 + l * 2];
            v4s wo = *(const v4s*)&wlds[2048 + f * 128 + l * 2];
            acc[ct] = __builtin_amdgcn_mfma_f32_16x16x16bf16_1k(a_agg, wr, acc[ct], 0, 0, 0);
            acc[ct] = __builtin_amdgcn_mfma_f32_16x16x16bf16_1k(ax[kt], wo, acc[ct], 0, 0, 0);
        }
    }
    // ---- MFMA pass 2: rows 16..23 (A rows replicated x2; keep D rows 0..7) ----
    const int r2row = 16 + (l & 7);
    v4s ax2[4];
    #pragma unroll
    for (int kt = 0; kt < 4; kt++)
        ax2[kt] = *(const v4s*)&xb[(node0w + r2row) * 32 + kt * 8 + g16 * 2];
    v4f acc2[4];
    #pragma unroll
    for (int ct = 0; ct < 4; ct++) acc2[ct] = (v4f){0.f, 0.f, 0.f, 0.f};
    #pragma unroll
    for (int kt = 0; kt < 4; kt++) {
        v4s a_agg2 = *(const v4s*)&agg_s[(w * NPW + r2row) * 72 + kt * 16 + g4];
        #pragma unroll
        for (int ct = 0; ct < 4; ct++) {
            int f = kt * 4 + ct;
            v4s wr = *(const v4s*)&wlds[f * 128 + l * 2];
            v4s wo = *(const v4s*)&wlds[2048 + f * 128 + l * 2];
            acc2[ct] = __builtin_amdgcn_mfma_f32_16x16x16bf16_1k(a_agg2, wr, acc2[ct], 0, 0, 0);
            acc2[ct] = __builtin_amdgcn_mfma_f32_16x16x16bf16_1k(ax2[kt], wo, acc2[ct], 0, 0, 0);
        }
    }
    __builtin_amdgcn_wave_barrier();

    // ---- epilogue into own agg rows ----
    #pragma unroll
    for (int ct = 0; ct < 4; ct++) {
        #pragma unroll
        for (int r = 0; r < 4; r++)
            agg_s[(w * NPW + g4 + r) * 72 + ct * 16 + lrow] = f2bf(acc[ct][r] + bv[ct]);
    }
    if (g16 < 2) {   // pass-2 valid D rows 0..7 -> nodes 16..23
        #pragma unroll
        for (int ct = 0; ct < 4; ct++) {
            #pragma unroll
            for (int r = 0; r < 4; r++)
                agg_s[(w * NPW + 16 + g4 + r) * 72 + ct * 16 + lrow] =
                    f2bf(acc2[ct][r] + bv[ct]);
        }
    }
    __builtin_amdgcn_wave_barrier();

    // ---- wave-local coalesced writeout: rows 0..15, then rows 16..23 ----
    {
        int row = l >> 2, qq = l & 3;
        const unsigned int* srcp = (const unsigned int*)&agg_s[(w * NPW + row) * 72 + qq * 16];
        uint4 v0 = *(const uint4*)(srcp);
        uint4 v1 = *(const uint4*)(srcp + 4);
        *(uint4*)&xob[(node0w + row) * 32 + qq * 8] = v0;
        *(uint4*)&xob[(node0w + row) * 32 + qq * 8 + 4] = v1;
    }
    {
        int row = 16 + (l >> 3), qq = l & 7;
        *(uint4*)&xob[(node0w + row) * 32 + qq * 4] =
            *(const uint4*)&agg_s[(w * NPW + row) * 72 + qq * 8];
    }
}

// ---------------- conv layer 3 (ligand rows only) + fused pooling ----------------
__global__ __launch_bounds__(512, 6) void conv_lig_kernel(const int* __restrict__ off,
                                                          const int* __restrict__ ends,
                                                          const int* __restrict__ csr,
                                                          const unsigned int* __restrict__ xb,
                                                          const unsigned short* __restrict__ wbuf,
                                                          const float* __restrict__ brel,
                                                          const int* __restrict__ lig_batch,
                                                          float* __restrict__ pooled,
                                                          float* __restrict__ cnt) {
    __shared__ unsigned int wlds[4096];          // 16 KB
    __shared__ unsigned short agg_s[8 * 8 * 72]; // 9 KB
    const int tid = threadIdx.x;
    const int w = tid >> 6, l = tid & 63;
    const unsigned int* wsrc = (const unsigned int*)wbuf;
    #pragma unroll
    for (int i = 0; i < 8; i++) wlds[i * 512 + tid] = wsrc[i * 512 + tid];

    const int s = l >> 3, q = l & 7;
    const int lrow = l & 15, g16 = l >> 4, g4 = 4 * (l >> 4);
    const int gwid = blockIdx.x * 8 + w;
    const int node0w = gwid * 8;

    int bvv = (l < 8) ? off[node0w + l] : 0;
    int evv = (l < 8) ? ends[node0w + l] : 0;
    int b0 = __shfl(bvv, s), d0 = __shfl(evv, s) - b0;
    int id0 = (q < d0) ? csr[b0 + q] : -1;

    __syncthreads();   // wlds ready

    float bv[4];
    #pragma unroll
    for (int ct = 0; ct < 4; ct++) bv[ct] = brel[ct * 16 + lrow];

    DO_GROUP(b0, d0, id0, w * 8 + s)

    __builtin_amdgcn_wave_barrier();

    // ---- MFMA: A rows duplicated (row = lrow&7) -> D rows 0..7 valid ----
    const int arow = lrow & 7;
    v4s ax[4];
    #pragma unroll
    for (int kt = 0; kt < 4; kt++)
        ax[kt] = *(const v4s*)&xb[(node0w + arow) * 32 + kt * 8 + g16 * 2];
    v4f acc[4];
    #pragma unroll
    for (int ct = 0; ct < 4; ct++) acc[ct] = (v4f){0.f, 0.f, 0.f, 0.f};
    #pragma unroll
    for (int kt = 0; kt < 4; kt++) {
        v4s a_agg = *(const v4s*)&agg_s[(w * 8 + arow) * 72 + kt * 16 + g4];
        #pragma unroll
        for (int ct = 0; ct < 4; ct++) {
            int f = kt * 4 + ct;
            v4s wr = *(const v4s*)&wlds[f * 128 + l * 2];
            v4s wo = *(const v4s*)&wlds[2048 + f * 128 + l * 2];
            acc[ct] = __builtin_amdgcn_mfma_f32_16x16x16bf16_1k(a_agg, wr, acc[ct], 0, 0, 0);
            acc[ct] = __builtin_amdgcn_mfma_f32_16x16x16bf16_1k(ax[kt], wo, acc[ct], 0, 0, 0);
        }
    }

    // ---- fused pooling epilogue (f32 atomics; D rows 0..7 only) ----
    if (g16 < 2) {
        #pragma unroll
        for (int r = 0; r < 4; r++) {
            int node = node0w + g4 + r;
            int bb = lig_batch[node];
            #pragma unroll
            for (int ct = 0; ct < 4; ct++)
                unsafeAtomicAdd(&pooled[bb * H + ct * 16 + lrow], acc[ct][r] + bv[ct]);
            if (lrow == 0) unsafeAtomicAdd(&cnt[bb], 1.0f);
        }
    }
}

// ---------------- readout ----------------
__global__ void readout_kernel(const float* __restrict__ pooled, const float* __restrict__ cnt,
                               const float* __restrict__ Wro1, const float* __restrict__ bro1,
                               const float* __restrict__ Wro2, const float* __restrict__ bro2,
                               float* __restrict__ out) {
    __shared__ float pm[4][H];
    int w = threadIdx.x >> 6;
    int h = threadIdx.x & 63;
    int b = blockIdx.x * 4 + w;
    float c = fmaxf(cnt[b], 1.0f);
    pm[w][h] = pooled[b * H + h] / c;
    __syncthreads();
    float acc = bro1[h];
    #pragma unroll 8
    for (int k = 0; k < H; k++) acc += pm[w][k] * Wro1[k * H + h];
    float sig = 1.0f / (1.0f + expf(-acc));
    float s = acc * sig;
    float r = s * Wro2[h];
    #pragma unroll
    for (int off = 32; off; off >>= 1) r += __shfl_down(r, off);
    if (h == 0) out[b] = r + bro2[0];
}

extern "C" void kernel_launch(void* const* d_in, const int* in_sizes, int n_in,
                              void* d_out, int out_size, void* d_ws, size_t ws_size,
                              hipStream_t stream) {
    const float* lig_feat  = (const float*)d_in[1];
    const float* prot_feat = (const float*)d_in[3];
    const float* t         = (const float*)d_in[4];
    const int*   lig_batch = (const int*)d_in[5];
    const int*   edge_index= (const int*)d_in[7];
    const float* W_lig  = (const float*)d_in[8];
    const float* b_lig  = (const float*)d_in[9];
    const float* W_prot = (const float*)d_in[10];
    const float* b_prot = (const float*)d_in[11];
    const float* Wt1 = (const float*)d_in[12];
    const float* bt1 = (const float*)d_in[13];
    const float* Wt2 = (const float*)d_in[14];
    const float* bt2 = (const float*)d_in[15];
    const float* Wrel[3]  = {(const float*)d_in[16], (const float*)d_in[19], (const float*)d_in[22]};
    const float* brel[3]  = {(const float*)d_in[17], (const float*)d_in[20], (const float*)d_in[23]};
    const float* Wroot[3] = {(const float*)d_in[18], (const float*)d_in[21], (const float*)d_in[24]};
    const float* Wro1 = (const float*)d_in[25];
    const float* bro1 = (const float*)d_in[26];
    const float* Wro2 = (const float*)d_in[27];
    const float* bro2 = (const float*)d_in[28];
    float* out = (float*)d_out;

    char* ws = (char*)d_ws;
    int*            off_a   = (int*)(ws);                       // NTOT ints
    int*            ends_a  = (int*)(ws + 655360);              // NTOT ints
    unsigned int*   bcursor = (unsigned int*)(ws + 1310720);    // 2304 B   ┐ contiguous
    float*          pooled  = (float*)(ws + 1313024);           // 65536 B  │ zero region
    float*          cnt     = (float*)(ws + 1378560);           // 1024 B   ┘ 68864 B
    float*          t_emb   = (float*)(ws + 1380352);           // 64 KB
    unsigned short* wbuf    = (unsigned short*)(ws + 1572864);  // 48 KB
    int*            csr_src = (int*)(ws + 2097152);             // 10.6 MB padded
    unsigned int*   bucketed= (unsigned int*)(ws + 14680064);   // 10.6 MB padded
    unsigned int*   xb0     = (unsigned int*)(ws + 27262976);   // 18 MB
    unsigned int*   xb1     = (unsigned int*)(ws + 46137344);   // 18 MB

    // prep2: wswz || time_mlp || zero(bcursor,pooled,cnt)
    prep2_kernel<<<41, 1024, 0, stream>>>(t, Wt1, bt1, Wt2, bt2,
                                          Wrel[0], Wroot[0], Wrel[1], Wroot[1], Wrel[2], Wroot[2],
                                          wbuf, t_emb, bcursor);

    // fill (privatized, interleaved) || node_init : 128 groups x 11 = 1408 blocks
    fill_init_kernel<<<1408, 1024, 0, stream>>>(edge_index, bcursor, bucketed,
                                                lig_feat, prot_feat, lig_batch, t_emb,
                                                W_lig, b_lig, W_prot, b_prot, xb0);

    // per-bucket counting sort -> CSR (privatized)
    bucket_csr_kernel<<<NBUCK, 1024, 0, stream>>>(bucketed, bcursor, off_a, ends_a, csr_src);

    // ---- conv layers 1,2 (all nodes; round-12 proven config) ----
    conv_kernel<<<768, 512, 0, stream>>>(off_a, ends_a, csr_src, xb0,
                                         wbuf, brel[0], xb1);
    conv_kernel<<<768, 512, 0, stream>>>(off_a, ends_a, csr_src, xb1,
                                         wbuf + 8192, brel[1], xb0);
    // ---- conv layer 3: ligand rows only, fused pooling ----
    conv_lig_kernel<<<NLIG / 64, 512, 0, stream>>>(off_a, ends_a, csr_src, xb0,
                                                   wbuf + 16384, brel[2], lig_batch,
                                                   pooled, cnt);

    readout_kernel<<<NB / 4, 256, 0, stream>>>(pooled, cnt, Wro1, bro1, Wro2, bro2, out);
}